// Round 1
// baseline (95.956 us; speedup 1.0000x reference)
//
#include <hip/hip_runtime.h>
#include <hip/hip_bf16.h>

// Shapes: keypoints (8,5,2) f32, mesh_grid (1024,2) f32, W (10,512) f32,
// distance_matrix (1024,1024) i32 in [0,64). Output (8,8,1024,1024) f32.
//
// Reshape semantics: A (B,N,512) -> (B,8,N,64) row-major raw reshape:
//   n_orig = h*128 + (n_new>>3);  o = (n_new&7)*64 + k
// out[b,h,n,m] = A_new[b,h,n, dm[n,m]]

#define NN 1024

__global__ __launch_bounds__(256) void KR_RPE_10582799417497_kernel(
    const float* __restrict__ kp,    // (8,5,2) = 80
    const float* __restrict__ mesh,  // (1024,2)
    const float* __restrict__ W,     // (10,512)
    const int*   __restrict__ dm,    // (1024,1024)
    float* __restrict__ out)         // (8,8,1024,1024)
{
    const int n = blockIdx.x;   // n_new in [0,1024)
    const int t = threadIdx.x;  // 0..255

    __shared__ float A_s[64 * 64];  // [bh][k]

    // ---- gather indices for this thread's 4 output columns (kept in regs)
    const int4 kk = *(const int4*)(dm + (size_t)n * NN + t * 4);

    // ---- compute A[bh][k] for this n_new, in the reshaped layout
    const int n0 = n >> 3;          // n_orig base (h*128 + n0)
    const int oo = (n & 7) * 64;    // o base
    const int k  = t & 63;          // lane -> k   (coalesced W loads)
    const int wv = t >> 6;          // wave 0..3 -> bh group of 16

    float Wv[10];
#pragma unroll
    for (int f = 0; f < 10; ++f) Wv[f] = W[f * 512 + oo + k];

#pragma unroll
    for (int i = 0; i < 16; ++i) {
        const int bh = wv * 16 + i;
        const int b = bh >> 3, h = bh & 7;
        const int n_orig = h * 128 + n0;
        const float mx = mesh[n_orig * 2 + 0];
        const float my = mesh[n_orig * 2 + 1];
        float acc = 0.f;
#pragma unroll
        for (int p = 0; p < 5; ++p) {
            const float dx = mx - kp[b * 10 + p * 2 + 0];
            const float dy = my - kp[b * 10 + p * 2 + 1];
            acc += dx * Wv[p * 2 + 0] + dy * Wv[p * 2 + 1];
        }
        A_s[bh * 64 + k] = acc;
    }
    __syncthreads();

    // ---- gather + streaming stores: 64 rows (bh), 4 contiguous m per thread
    float* op = out + (size_t)n * NN + (size_t)t * 4;
#pragma unroll 4
    for (int bh = 0; bh < 64; ++bh) {
        const float* a = A_s + bh * 64;
        float4 v = make_float4(a[kk.x], a[kk.y], a[kk.z], a[kk.w]);
        *(float4*)(op + (size_t)bh * (NN * NN)) = v;
    }
}

extern "C" void kernel_launch(void* const* d_in, const int* in_sizes, int n_in,
                              void* d_out, int out_size, void* d_ws, size_t ws_size,
                              hipStream_t stream) {
    const float* kp   = (const float*)d_in[0];
    const float* mesh = (const float*)d_in[1];
    const float* W    = (const float*)d_in[2];
    const int*   dm   = (const int*)d_in[3];
    float* out = (float*)d_out;

    KR_RPE_10582799417497_kernel<<<NN, 256, 0, stream>>>(kp, mesh, W, dm, out);
}

// Round 3
// 61.126 us; speedup vs baseline: 1.5698x; 1.5698x over previous
//
#include <hip/hip_runtime.h>
#include <hip/hip_bf16.h>

// Shapes: keypoints (8,5,2) f32, mesh_grid (1024,2) f32, W (10,512) f32,
// distance_matrix (1024,1024) i32 in [0,64). Output (8,8,1024,1024) f32.
//
// Reshape semantics: A (B,N,512) -> (B,8,N,64) row-major raw reshape:
//   n_orig = h*128 + (n_new>>3);  o = (n_new&7)*64 + k
// out[b,h,n,m] = A_new[b,h,n, dm[n,m]]
//
// R2 design (= R1 + compile fix): no LDS. Each wave holds the 64-entry
// gather table for bh as one-element-per-lane registers (k = lane), gathers
// via ds_bpermute_b32 (crossbar, conflict-free), stores native float4
// nontemporally. Grid 4096 = 4 bh-quarters x 1024 n -> 32 waves/CU.

#define NN 1024

typedef float f32x4 __attribute__((ext_vector_type(4)));

__global__ __launch_bounds__(256) void KR_RPE_10582799417497_kernel(
    const float* __restrict__ kp,    // (8,5,2)
    const float* __restrict__ mesh,  // (1024,2)
    const float* __restrict__ W,     // (10,512)
    const int*   __restrict__ dm,    // (1024,1024)
    float* __restrict__ out)         // (8,8,1024,1024)
{
    const int bid  = blockIdx.x;
    const int n    = bid & (NN - 1);  // n_new
    const int q    = bid >> 10;      // bh quarter 0..3
    const int t    = threadIdx.x;
    const int lane = t & 63;
    const int w    = t >> 6;         // wave 0..3 -> m chunk of 256

    const int n0 = n >> 3;           // n_orig = h*128 + n0
    const int oo = (n & 7) * 64;     // o base
    const int k  = lane;             // this lane's table column

    // W column slice for k (coalesced: lane i -> consecutive floats)
    float Wv[10];
#pragma unroll
    for (int f = 0; f < 10; ++f) Wv[f] = W[f * 512 + oo + k];

    // 16-entry register table: tab[i] = A[bh=q*16+i][k=lane]
    float tab[16];
#pragma unroll
    for (int i = 0; i < 16; ++i) {
        const int bh = q * 16 + i;
        const int b = bh >> 3, h = bh & 7;
        const int n_orig = h * 128 + n0;
        const float mx = mesh[n_orig * 2 + 0];   // wave-uniform
        const float my = mesh[n_orig * 2 + 1];
        float acc = 0.f;
#pragma unroll
        for (int p = 0; p < 5; ++p) {
            acc += (mx - kp[b * 10 + p * 2 + 0]) * Wv[p * 2 + 0]
                 + (my - kp[b * 10 + p * 2 + 1]) * Wv[p * 2 + 1];
        }
        tab[i] = acc;
    }

    // gather indices: this lane's 4 consecutive m values (coalesced int4)
    const int mbase = w * 256;
    const int4 kk = *(const int4*)(dm + (size_t)n * NN + mbase + lane * 4);
    const int ax = kk.x * 4, ay = kk.y * 4, az = kk.z * 4, aw = kk.w * 4;

    // out[(bh*NN + n)*NN + m],  m = mbase + lane*4 + {0..3}
    float* op = out + ((size_t)(q * 16) * NN + n) * NN + mbase + lane * 4;

#pragma unroll
    for (int i = 0; i < 16; ++i) {
        const int s = __float_as_int(tab[i]);
        f32x4 v;
        v.x = __int_as_float(__builtin_amdgcn_ds_bpermute(ax, s));
        v.y = __int_as_float(__builtin_amdgcn_ds_bpermute(ay, s));
        v.z = __int_as_float(__builtin_amdgcn_ds_bpermute(az, s));
        v.w = __int_as_float(__builtin_amdgcn_ds_bpermute(aw, s));
        __builtin_nontemporal_store(v, (f32x4*)(op + (size_t)i * (NN * (size_t)NN)));
    }
}

extern "C" void kernel_launch(void* const* d_in, const int* in_sizes, int n_in,
                              void* d_out, int out_size, void* d_ws, size_t ws_size,
                              hipStream_t stream) {
    const float* kp   = (const float*)d_in[0];
    const float* mesh = (const float*)d_in[1];
    const float* W    = (const float*)d_in[2];
    const int*   dm   = (const int*)d_in[3];
    float* out = (float*)d_out;

    KR_RPE_10582799417497_kernel<<<4 * NN, 256, 0, stream>>>(kp, mesh, W, dm, out);
}

// Round 5
// 47.581 us; speedup vs baseline: 2.0167x; 1.2847x over previous
//
#include <hip/hip_runtime.h>
#include <hip/hip_bf16.h>

// Shapes: keypoints (8,5,2) f32, mesh_grid (1024,2) f32, W (10,512) f32,
// distance_matrix (1024,1024) i32 in [0,64). Output (8,8,1024,1024) f32.
//
// Reshape semantics: A (B,N,512) -> (B,8,N,64) row-major raw reshape:
//   n_orig = h*128 + (n_new>>3);  o = (n_new&7)*64 + k
// out[b,h,n,m] = A_new[b,h,n, dm[n,m]]
//
// R4 = R3 with store-stride fix (it*256, was it*1024 -> OOB write + overlap).
// One WAVE = one contiguous 4 KB output row (plane bh, row n). Table in one
// register (k = lane); gather via ds_bpermute (conflict-free); 4 x 1 KB
// float4 nontemporal stores. blockIdx n-fast so co-resident blocks write
// consecutive rows of the same 4 planes (fill-like linear streams).

#define NN 1024

typedef float f32x4 __attribute__((ext_vector_type(4)));

__global__ __launch_bounds__(256) void KR_RPE_10582799417497_kernel(
    const float* __restrict__ kp,    // (8,5,2)
    const float* __restrict__ mesh,  // (1024,2)
    const float* __restrict__ W,     // (10,512)
    const int*   __restrict__ dm,    // (1024,1024)
    float* __restrict__ out)         // (8,8,1024,1024)
{
    const int bid  = blockIdx.x;
    const int g    = bid >> 10;       // plane group 0..15 (slow)
    const int n    = bid & (NN - 1);  // row 0..1023 (fast)
    const int t    = threadIdx.x;
    const int lane = t & 63;
    const int w    = t >> 6;          // wave 0..3
    const int bh   = g * 4 + w;       // this wave's output plane
    const int b    = bh >> 3, h = bh & 7;

    const int n0 = n >> 3;            // n_orig = h*128 + n0
    const int oo = (n & 7) * 64;      // o base
    const int k  = lane;              // this lane's table column

    // W column slice for k (coalesced 256 B per load)
    float Wv[10];
#pragma unroll
    for (int f = 0; f < 10; ++f) Wv[f] = W[f * 512 + oo + k];

    // one-register gather table: A[bh][k = lane]
    const int n_orig = h * 128 + n0;
    const float mx = mesh[n_orig * 2 + 0];
    const float my = mesh[n_orig * 2 + 1];
    float acc = 0.f;
#pragma unroll
    for (int p = 0; p < 5; ++p) {
        acc += (mx - kp[b * 10 + p * 2 + 0]) * Wv[p * 2 + 0]
             + (my - kp[b * 10 + p * 2 + 1]) * Wv[p * 2 + 1];
    }
    const int s = __float_as_int(acc);

    const int* dr = dm + (size_t)n * NN;              // shared by all 4 waves (L1)
    float* op = out + ((size_t)bh * NN + n) * NN;     // this wave's 4 KB row

#pragma unroll
    for (int it = 0; it < 4; ++it) {
        const int4 kk = *(const int4*)(dr + it * 256 + lane * 4);
        f32x4 v;
        v.x = __int_as_float(__builtin_amdgcn_ds_bpermute(kk.x * 4, s));
        v.y = __int_as_float(__builtin_amdgcn_ds_bpermute(kk.y * 4, s));
        v.z = __int_as_float(__builtin_amdgcn_ds_bpermute(kk.z * 4, s));
        v.w = __int_as_float(__builtin_amdgcn_ds_bpermute(kk.w * 4, s));
        __builtin_nontemporal_store(v, (f32x4*)(op + it * 256 + lane * 4));
    }
}

extern "C" void kernel_launch(void* const* d_in, const int* in_sizes, int n_in,
                              void* d_out, int out_size, void* d_ws, size_t ws_size,
                              hipStream_t stream) {
    const float* kp   = (const float*)d_in[0];
    const float* mesh = (const float*)d_in[1];
    const float* W    = (const float*)d_in[2];
    const int*   dm   = (const int*)d_in[3];
    float* out = (float*)d_out;

    KR_RPE_10582799417497_kernel<<<16 * NN, 256, 0, stream>>>(kp, mesh, W, dm, out);
}